// Round 2
// baseline (424.669 us; speedup 1.0000x reference)
//
#include <hip/hip_runtime.h>
#include <hip/hip_bf16.h>
#include <cstdint>
#include <cstddef>

// B=2, T=2048, D=1024, H=16, DH=64, CTX=2048.  M = B*T = 4096.

using bf16x8 = __attribute__((ext_vector_type(8))) __bf16;
using f32x4  = __attribute__((ext_vector_type(4))) float;

__device__ __forceinline__ short f2b(float f) {
  uint32_t u = __builtin_bit_cast(uint32_t, f);
  uint32_t r = (u + 0x7FFFu + ((u >> 16) & 1u)) >> 16;
  return (short)r;
}
__device__ __forceinline__ float b2f(short s) {
  uint32_t u = ((uint32_t)(uint16_t)s) << 16;
  return __builtin_bit_cast(float, u);
}

__device__ __forceinline__ void gload16(const short* g, short* l) {
  __builtin_amdgcn_global_load_lds(
      (const __attribute__((address_space(1))) void*)g,
      (__attribute__((address_space(3))) void*)l, 16, 0, 0);
}

__device__ __forceinline__ f32x4 mma16(bf16x8 a, bf16x8 b, f32x4 c) {
  return __builtin_amdgcn_mfma_f32_16x16x32_bf16(a, b, c, 0, 0, 0);
}

// ---------------------------------------------------------------------------
// Staging for ROWSx64 tiles (attention kernel), XOR swizzle on global source.
// ---------------------------------------------------------------------------
template<int ROWS>
__device__ __forceinline__ void stage_swz(const short* __restrict__ g, int ldg,
                                          short* lds, int tid) {
#pragma unroll
  for (int jj = 0; jj < ROWS / 32; ++jj) {
    int row = jj * 32 + (tid >> 3);
    int seg = tid & 7;
    int ss  = seg ^ (row & 7);
    gload16(g + (size_t)row * ldg + ss * 8, lds + row * 64 + (seg << 3));
  }
}

// ---------------------------------------------------------------------------
// Staging for ROWSx32 tiles (GEMM pipeline).  THREADS threads, NLOADS gload16
// per thread; each wave-load covers 16 rows (linear lane*16B dest); global
// source pre-swizzled: LDS[row][seg] <- global seg ^ (row&3).
// ---------------------------------------------------------------------------
template<int THREADS, int NLOADS>
__device__ __forceinline__ void stage_t32(const short* __restrict__ g, int ldg,
                                          short* lds, int tid) {
#pragma unroll
  for (int j = 0; j < NLOADS; ++j) {
    int row = (tid >> 2) + j * (THREADS / 4);
    int seg = tid & 3;
    gload16(g + (size_t)row * ldg + ((seg ^ (row & 3)) << 3),
            lds + row * 32 + (seg << 3));
  }
}

__device__ __forceinline__ bf16x8 frag32(const short* lds, int row, int seg) {
  return *(const bf16x8*)(lds + row * 32 + ((seg ^ (row & 3)) << 3));
}

// ---------------------------------------------------------------------------
// Fused weight conversion f32 -> bf16 (all 5 weights in one dispatch).
// block ranges: [0,3072) qkv | [3072,4096) proj | [4096,8192) gate
//               [8192,12288) up | [12288,16384) down
// ---------------------------------------------------------------------------
__global__ void k_cvt_all(const float* __restrict__ wqkv, short* __restrict__ oqkv,
                          const float* __restrict__ wproj, short* __restrict__ oproj,
                          const float* __restrict__ wgate, short* __restrict__ ogate,
                          const float* __restrict__ wup, short* __restrict__ oup,
                          const float* __restrict__ wdown, short* __restrict__ odown) {
  int bid = blockIdx.x;
  const float* src;
  short* dst;
  int off;
  if (bid < 3072)       { src = wqkv;  dst = oqkv;  off = bid; }
  else if (bid < 4096)  { src = wproj; dst = oproj; off = bid - 3072; }
  else if (bid < 8192)  { src = wgate; dst = ogate; off = bid - 4096; }
  else if (bid < 12288) { src = wup;   dst = oup;   off = bid - 8192; }
  else                  { src = wdown; dst = odown; off = bid - 12288; }
  int i = off * 256 + threadIdx.x;
  float4 v = ((const float4*)src)[i];
  ((short4*)dst)[i] = make_short4(f2b(v.x), f2b(v.y), f2b(v.z), f2b(v.w));
}

// ---------------------------------------------------------------------------
// RMSNorm: one block (256 thr) per row of 1024 f32 -> bf16
// ---------------------------------------------------------------------------
__global__ void k_rms(const float* __restrict__ x, const float* __restrict__ w,
                      short* __restrict__ out) {
  int row = blockIdx.x;
  int tid = threadIdx.x;
  float4 v = *(const float4*)(x + (size_t)row * 1024 + tid * 4);
  float ss = v.x * v.x + v.y * v.y + v.z * v.z + v.w * v.w;
#pragma unroll
  for (int o = 1; o < 64; o <<= 1) ss += __shfl_xor(ss, o);
  __shared__ float sred[4];
  int wid = tid >> 6, lane = tid & 63;
  if (lane == 0) sred[wid] = ss;
  __syncthreads();
  float tot = sred[0] + sred[1] + sred[2] + sred[3];
  float r = rsqrtf(tot * (1.0f / 1024.0f) + 1e-6f);
  float4 wv = *(const float4*)(w + tid * 4);
  short4 o = make_short4(f2b(v.x * r * wv.x), f2b(v.y * r * wv.y),
                         f2b(v.z * r * wv.z), f2b(v.w * r * wv.w));
  *(short4*)(out + (size_t)row * 1024 + tid * 4) = o;
}

// ---------------------------------------------------------------------------
// Big pipelined GEMM: C[M,N] = A[M,K] * W[N,K]^T, 256x256 tile, BK=32,
// ring-4 LDS, 8 waves (512 thr), counted vmcnt, raw barriers, setprio.
// MODE 1: outb = bf16(C)                 (gate)
// MODE 2: outb = bf16(silu(outb) * C)    (up, fused with gate)
// MODE 3: QKV epilogue -> q_b/k_b/vT_b bf16 + k/v caches f32
// ---------------------------------------------------------------------------
template<int MODE>
__global__ __launch_bounds__(512, 2) void k_gemm_big(
    const short* __restrict__ A, const short* __restrict__ Bw,
    int M, int N, int K, int gx,
    const float* __restrict__ res, float* __restrict__ outf,
    short* __restrict__ outb,
    short* __restrict__ q_b, short* __restrict__ k_b, short* __restrict__ vT_b,
    float* __restrict__ kc, float* __restrict__ vc) {
  __shared__ short As[4][256 * 32];  // 64 KB
  __shared__ short Bs[4][256 * 32];  // 64 KB
  int tid = threadIdx.x;
  // XCD-aware swizzle (grid % 8 == 0 guaranteed by launch)
  int nwg = gridDim.x;
  int bid = blockIdx.x;
  int swz = (bid & 7) * (nwg >> 3) + (bid >> 3);
  int bx = swz % gx, by = swz / gx;
  int m0 = by * 256, n0 = bx * 256;
  int w = tid >> 6, l = tid & 63;
  int wr = w >> 2, wc = w & 3;
  f32x4 acc[8][4] = {};
  int nk = K >> 5;
  const short* Ab = A + (size_t)m0 * K;
  const short* Bb = Bw + (size_t)n0 * K;
#pragma unroll 1
  for (int p = 0; p < 3; ++p) {
    stage_t32<512, 2>(Ab + p * 32, K, &As[p][0], tid);
    stage_t32<512, 2>(Bb + p * 32, K, &Bs[p][0], tid);
  }
#pragma unroll 1
  for (int n = 0; n < nk; ++n) {
    int bb = n & 3;
    // wait: only tiles n+1, n+2 may remain in flight (4 loads/wave/tile)
    asm volatile("s_waitcnt vmcnt(8)\n\ts_barrier" ::: "memory");
    if (n + 3 < nk) {
      int pb = (n + 3) & 3;
      stage_t32<512, 2>(Ab + (n + 3) * 32, K, &As[pb][0], tid);
      stage_t32<512, 2>(Bb + (n + 3) * 32, K, &Bs[pb][0], tid);
    }
    bf16x8 a[8], b[4];
    int seg = l >> 4;
#pragma unroll
    for (int i = 0; i < 8; ++i)
      a[i] = frag32(&As[bb][0], wr * 128 + i * 16 + (l & 15), seg);
#pragma unroll
    for (int j = 0; j < 4; ++j)
      b[j] = frag32(&Bs[bb][0], wc * 64 + j * 16 + (l & 15), seg);
    __builtin_amdgcn_s_setprio(1);
#pragma unroll
    for (int i = 0; i < 8; ++i)
#pragma unroll
      for (int j = 0; j < 4; ++j)
        acc[i][j] = mma16(a[i], b[j], acc[i][j]);
    __builtin_amdgcn_s_setprio(0);
  }
  // epilogue: C frag layout col = l&15, row = (l>>4)*4 + r
#pragma unroll
  for (int i = 0; i < 8; ++i) {
#pragma unroll
    for (int j = 0; j < 4; ++j) {
#pragma unroll
      for (int r = 0; r < 4; ++r) {
        int m = m0 + wr * 128 + i * 16 + (l >> 4) * 4 + r;
        int n = n0 + wc * 64 + j * 16 + (l & 15);
        float f = acc[i][j][r];
        if (MODE == 1) {
          outb[(size_t)m * N + n] = f2b(f);
        } else if (MODE == 2) {
          float g = b2f(outb[(size_t)m * N + n]);
          float s = g / (1.0f + __expf(-g));
          outb[(size_t)m * N + n] = f2b(s * f);
        } else {
          int jj = n >> 10, hh = (n >> 6) & 15, dh = n & 63;
          int b_ = m >> 11, t = m & 2047;
          int bh = b_ * 16 + hh;
          size_t idx = ((size_t)bh * 2048 + t) * 64 + dh;
          if (jj == 0) {
            q_b[idx] = f2b(f);
          } else if (jj == 1) {
            k_b[idx] = f2b(f);
            kc[idx] = f;
          } else {
            vT_b[((size_t)bh * 64 + dh) * 2048 + t] = f2b(f);
            vc[idx] = f;
          }
        }
      }
    }
  }
}

// ---------------------------------------------------------------------------
// Skinny pipelined GEMM: 256x64 tile, BK=32, ring-4, 4 waves (256 thr).
// outf[m,n] = C + res[m,n]   (proj and down, N=1024 -> grid 16x16)
// ---------------------------------------------------------------------------
__global__ __launch_bounds__(256, 2) void k_gemm_skinny(
    const short* __restrict__ A, const short* __restrict__ Bw,
    int M, int N, int K, int gx,
    const float* __restrict__ res, float* __restrict__ outf) {
  __shared__ short As[4][256 * 32];  // 64 KB
  __shared__ short Bs[4][64 * 32];   // 16 KB
  int tid = threadIdx.x;
  int nwg = gridDim.x;
  int bid = blockIdx.x;
  int swz = (bid & 7) * (nwg >> 3) + (bid >> 3);
  int bx = swz % gx, by = swz / gx;
  int m0 = by * 256, n0 = bx * 64;
  int w = tid >> 6, l = tid & 63;
  int wr = w >> 1, wc = w & 1;
  f32x4 acc[8][2] = {};
  int nk = K >> 5;
  const short* Ab = A + (size_t)m0 * K;
  const short* Bb = Bw + (size_t)n0 * K;
#pragma unroll 1
  for (int p = 0; p < 3; ++p) {
    stage_t32<256, 4>(Ab + p * 32, K, &As[p][0], tid);
    stage_t32<256, 1>(Bb + p * 32, K, &Bs[p][0], tid);
  }
#pragma unroll 1
  for (int n = 0; n < nk; ++n) {
    int bb = n & 3;
    // 5 loads/wave/tile -> tiles n+1,n+2 in flight = 10
    asm volatile("s_waitcnt vmcnt(10)\n\ts_barrier" ::: "memory");
    if (n + 3 < nk) {
      int pb = (n + 3) & 3;
      stage_t32<256, 4>(Ab + (n + 3) * 32, K, &As[pb][0], tid);
      stage_t32<256, 1>(Bb + (n + 3) * 32, K, &Bs[pb][0], tid);
    }
    bf16x8 a[8], b[2];
    int seg = l >> 4;
#pragma unroll
    for (int i = 0; i < 8; ++i)
      a[i] = frag32(&As[bb][0], wr * 128 + i * 16 + (l & 15), seg);
#pragma unroll
    for (int j = 0; j < 2; ++j)
      b[j] = frag32(&Bs[bb][0], wc * 32 + j * 16 + (l & 15), seg);
    __builtin_amdgcn_s_setprio(1);
#pragma unroll
    for (int i = 0; i < 8; ++i)
#pragma unroll
      for (int j = 0; j < 2; ++j)
        acc[i][j] = mma16(a[i], b[j], acc[i][j]);
    __builtin_amdgcn_s_setprio(0);
  }
#pragma unroll
  for (int i = 0; i < 8; ++i) {
#pragma unroll
    for (int j = 0; j < 2; ++j) {
#pragma unroll
      for (int r = 0; r < 4; ++r) {
        int m = m0 + wr * 128 + i * 16 + (l >> 4) * 4 + r;
        int n = n0 + wc * 32 + j * 16 + (l & 15);
        outf[(size_t)m * N + n] = acc[i][j][r] + res[(size_t)m * N + n];
      }
    }
  }
}

// ---------------------------------------------------------------------------
// Causal flash attention (unchanged from round 1).
// ---------------------------------------------------------------------------
__global__ __launch_bounds__(256) void k_attn(const short* __restrict__ q_b,
                                              const short* __restrict__ k_b,
                                              const short* __restrict__ vT_b,
                                              short* __restrict__ o_b) {
  __shared__ short Qs[64 * 64];
  __shared__ short Ks[64 * 64];
  __shared__ short VTs[64 * 64];
  __shared__ short Ps[4][16 * 88];
  int tid = threadIdx.x;
  int w = tid >> 6, l = tid & 63;
  int qt = blockIdx.x, bh = blockIdx.y;
  int q0 = qt * 64;

  stage_swz<64>(q_b + ((size_t)bh * 2048 + q0) * 64, 64, Qs, tid);

  f32x4 acc[4] = {};
  float mrow = -INFINITY, dden = 0.0f;
  int qg = q0 + w * 16 + (l & 15);
  int nt = qt + 1;

  for (int kt = 0; kt < nt; ++kt) {
    int kv0 = kt * 64;
    __syncthreads();
    stage_swz<64>(k_b + ((size_t)bh * 2048 + kv0) * 64, 64, Ks, tid);
    stage_swz<64>(vT_b + (size_t)bh * 64 * 2048 + kv0, 2048, VTs, tid);
    __syncthreads();

    bf16x8 qf[2];
#pragma unroll
    for (int kk = 0; kk < 2; ++kk) {
      int rowq = w * 16 + (l & 15);
      int s = kk * 4 + (l >> 4);
      qf[kk] = *(const bf16x8*)(Qs + rowq * 64 + ((s ^ (rowq & 7)) << 3));
    }
    f32x4 st[4];
#pragma unroll
    for (int i = 0; i < 4; ++i) {
      f32x4 z = {};
#pragma unroll
      for (int kk = 0; kk < 2; ++kk) {
        int rowk = i * 16 + (l & 15);
        int s = kk * 4 + (l >> 4);
        bf16x8 kf = *(const bf16x8*)(Ks + rowk * 64 + ((s ^ (rowk & 7)) << 3));
        z = mma16(kf, qf[kk], z);
      }
      st[i] = z;
    }

    float p[16];
    float pm = -INFINITY;
    bool last = (kt == qt);
#pragma unroll
    for (int i = 0; i < 4; ++i)
#pragma unroll
      for (int r = 0; r < 4; ++r) {
        int key = kv0 + i * 16 + (l >> 4) * 4 + r;
        float v = st[i][r] * 0.125f;
        if (last && key > qg) v = -INFINITY;
        p[i * 4 + r] = v;
        pm = fmaxf(pm, v);
      }
    pm = fmaxf(pm, __shfl_xor(pm, 16));
    pm = fmaxf(pm, __shfl_xor(pm, 32));
    float nm = fmaxf(mrow, pm);
    float corr = __expf(mrow - nm);
    float ds_ = 0.0f;
#pragma unroll
    for (int kx = 0; kx < 16; ++kx) {
      float pv = __expf(p[kx] - nm);
      p[kx] = pv;
      ds_ += pv;
    }
    ds_ += __shfl_xor(ds_, 16);
    ds_ += __shfl_xor(ds_, 32);
    dden = dden * corr + ds_;
    mrow = nm;
#pragma unroll
    for (int r = 0; r < 4; ++r) {
      float cr = __shfl(corr, (l >> 4) * 4 + r);
#pragma unroll
      for (int jf = 0; jf < 4; ++jf) acc[jf][r] *= cr;
    }

    short* pw = &Ps[w][0];
#pragma unroll
    for (int i = 0; i < 4; ++i) {
      uint32_t lo = (uint32_t)(uint16_t)f2b(p[i * 4 + 0]) |
                    ((uint32_t)(uint16_t)f2b(p[i * 4 + 1]) << 16);
      uint32_t hi = (uint32_t)(uint16_t)f2b(p[i * 4 + 2]) |
                    ((uint32_t)(uint16_t)f2b(p[i * 4 + 3]) << 16);
      uint2 pk;
      pk.x = lo;
      pk.y = hi;
      *(uint2*)(pw + (l & 15) * 88 + i * 16 + ((l >> 4) << 2)) = pk;
    }

#pragma unroll
    for (int kk = 0; kk < 2; ++kk) {
      bf16x8 pa = *(const bf16x8*)(pw + (l & 15) * 88 + kk * 32 + ((l >> 4) << 3));
#pragma unroll
      for (int jf = 0; jf < 4; ++jf) {
        int rowv = jf * 16 + (l & 15);
        int s = kk * 4 + (l >> 4);
        bf16x8 vb = *(const bf16x8*)(VTs + rowv * 64 + ((s ^ (rowv & 7)) << 3));
        acc[jf] = mma16(pa, vb, acc[jf]);
      }
    }
  }

  int hh = bh & 15, b_ = bh >> 4;
#pragma unroll
  for (int r = 0; r < 4; ++r) {
    float dq = __shfl(dden, (l >> 4) * 4 + r);
    float inv = 1.0f / dq;
    int mg = q0 + w * 16 + (l >> 4) * 4 + r;
    size_t rowoff = ((size_t)b_ * 2048 + mg) * 1024 + hh * 64;
#pragma unroll
    for (int jf = 0; jf < 4; ++jf)
      o_b[rowoff + jf * 16 + (l & 15)] = f2b(acc[jf][r] * inv);
  }
}

// ---------------------------------------------------------------------------
// Launch
// ---------------------------------------------------------------------------
extern "C" void kernel_launch(void* const* d_in, const int* in_sizes, int n_in,
                              void* d_out, int out_size, void* d_ws, size_t ws_size,
                              hipStream_t stream) {
  const float* x     = (const float*)d_in[0];
  const float* wn1   = (const float*)d_in[1];
  const float* wqkv  = (const float*)d_in[2];
  const float* wproj = (const float*)d_in[3];
  const float* wn2   = (const float*)d_in[4];
  const float* wgate = (const float*)d_in[5];
  const float* wup   = (const float*)d_in[6];
  const float* wdown = (const float*)d_in[7];
  float* out = (float*)d_out;
  char* ws = (char*)d_ws;

  short* wqkv_b  = (short*)(ws + 0);         //  6 MB
  short* wproj_b = (short*)(ws + 6291456);   //  2 MB
  short* wgate_b = (short*)(ws + 8388608);   //  8 MB
  short* wup_b   = (short*)(ws + 16777216);  //  8 MB
  short* wdown_b = (short*)(ws + 25165824);  //  8 MB
  short* h_b     = (short*)(ws + 33554432);  //  8 MB (h, then h2)
  short* q_b     = (short*)(ws + 41943040);  //  8 MB
  short* k_b     = (short*)(ws + 50331648);  //  8 MB
  short* vT_b    = (short*)(ws + 58720256);  //  8 MB
  short* ao_b    = (short*)(ws + 67108864);  //  8 MB
  short* act_b   = q_b;   // 32 MB alias over q/k/vT/ao (free after attention)
  float* x1 = out;
  float* kc = out + 4194304;
  float* vc = out + 8388608;

  k_cvt_all<<<16384, 256, 0, stream>>>(wqkv, wqkv_b, wproj, wproj_b,
                                       wgate, wgate_b, wup, wup_b, wdown, wdown_b);

  k_rms<<<4096, 256, 0, stream>>>(x, wn1, h_b);

  // qkv = h @ w_qkv^T  (grid 12x16 = 192 blocks)
  k_gemm_big<3><<<192, 512, 0, stream>>>(h_b, wqkv_b, 4096, 3072, 1024, 12,
                                         nullptr, nullptr, nullptr,
                                         q_b, k_b, vT_b, kc, vc);

  k_attn<<<dim3(32, 32), 256, 0, stream>>>(q_b, k_b, vT_b, ao_b);

  // x1 = x + attn @ w_proj^T  (grid 16x16 = 256 blocks)
  k_gemm_skinny<<<256, 256, 0, stream>>>(ao_b, wproj_b, 4096, 1024, 1024, 16,
                                         x, x1);

  k_rms<<<4096, 256, 0, stream>>>(x1, wn2, h_b);

  // gate = h2 @ w_gate^T (bf16)
  k_gemm_big<1><<<256, 512, 0, stream>>>(h_b, wgate_b, 4096, 4096, 1024, 16,
                                         nullptr, nullptr, act_b,
                                         nullptr, nullptr, nullptr, nullptr, nullptr);
  // act = silu(gate) * (h2 @ w_up^T)
  k_gemm_big<2><<<256, 512, 0, stream>>>(h_b, wup_b, 4096, 4096, 1024, 16,
                                         nullptr, nullptr, act_b,
                                         nullptr, nullptr, nullptr, nullptr, nullptr);
  // x_out = x1 + act @ w_down^T
  k_gemm_skinny<<<256, 256, 0, stream>>>(act_b, wdown_b, 4096, 1024, 4096, 16,
                                         x1, out);
}

// Round 3
// 358.501 us; speedup vs baseline: 1.1846x; 1.1846x over previous
//
#include <hip/hip_runtime.h>
#include <hip/hip_bf16.h>
#include <cstdint>
#include <cstddef>

// B=2, T=2048, D=1024, H=16, DH=64, CTX=2048.  M = B*T = 4096.

using bf16x8 = __attribute__((ext_vector_type(8))) __bf16;
using f32x4  = __attribute__((ext_vector_type(4))) float;

#define VMCNT(n) asm volatile("s_waitcnt vmcnt(" #n ")" ::: "memory")
#define LGKM0()  do { asm volatile("s_waitcnt lgkmcnt(0)" ::: "memory"); \
                      __builtin_amdgcn_sched_barrier(0); } while (0)
#define BARF()   do { asm volatile("" ::: "memory"); __builtin_amdgcn_s_barrier(); \
                      asm volatile("" ::: "memory"); } while (0)

__device__ __forceinline__ short f2b(float f) {
  uint32_t u = __builtin_bit_cast(uint32_t, f);
  uint32_t r = (u + 0x7FFFu + ((u >> 16) & 1u)) >> 16;
  return (short)r;
}
__device__ __forceinline__ float b2f(short s) {
  uint32_t u = ((uint32_t)(uint16_t)s) << 16;
  return __builtin_bit_cast(float, u);
}

__device__ __forceinline__ void gload16(const short* g, short* l) {
  __builtin_amdgcn_global_load_lds(
      (const __attribute__((address_space(1))) void*)g,
      (__attribute__((address_space(3))) void*)l, 16, 0, 0);
}

// ---------------------------------------------------------------------------
// Staging, 64-col (128B) rows, XOR (row&7) swizzle applied on GLOBAL source,
// linear LDS dest (global_load_lds requirement).  Zero-bank-conflict verified.
// ---------------------------------------------------------------------------
template<int ROWS>  // 256 threads, ROWS/32 loads per thread
__device__ __forceinline__ void stage_swz(const short* __restrict__ g, int ldg,
                                          short* lds, int tid) {
#pragma unroll
  for (int jj = 0; jj < ROWS / 32; ++jj) {
    int row = jj * 32 + (tid >> 3);
    int seg = tid & 7;
    gload16(g + (size_t)row * ldg + ((seg ^ (row & 7)) << 3),
            lds + row * 64 + (seg << 3));
  }
}

// 512 threads, one 64-row round per call
__device__ __forceinline__ void stage_round512(const short* __restrict__ g, int ldg,
                                               short* lds, int tid, int rbase) {
  int row = rbase + (tid >> 3);
  int seg = tid & 7;
  gload16(g + (size_t)row * ldg + ((seg ^ (row & 7)) << 3),
          lds + row * 64 + (seg << 3));
}

__device__ __forceinline__ bf16x8 frag64(const short* lds, int row, int seg) {
  return *(const bf16x8*)(lds + row * 64 + ((seg ^ (row & 7)) << 3));
}

__device__ __forceinline__ f32x4 mma16(bf16x8 a, bf16x8 b, f32x4 c) {
  return __builtin_amdgcn_mfma_f32_16x16x32_bf16(a, b, c, 0, 0, 0);
}

// ---------------------------------------------------------------------------
// Fused weight conversion f32 -> bf16
// ---------------------------------------------------------------------------
__global__ void k_cvt_all(const float* __restrict__ wqkv, short* __restrict__ oqkv,
                          const float* __restrict__ wproj, short* __restrict__ oproj,
                          const float* __restrict__ wgate, short* __restrict__ ogate,
                          const float* __restrict__ wup, short* __restrict__ oup,
                          const float* __restrict__ wdown, short* __restrict__ odown) {
  int bid = blockIdx.x;
  const float* src;
  short* dst;
  int off;
  if (bid < 3072)       { src = wqkv;  dst = oqkv;  off = bid; }
  else if (bid < 4096)  { src = wproj; dst = oproj; off = bid - 3072; }
  else if (bid < 8192)  { src = wgate; dst = ogate; off = bid - 4096; }
  else if (bid < 12288) { src = wup;   dst = oup;   off = bid - 8192; }
  else                  { src = wdown; dst = odown; off = bid - 12288; }
  int i = off * 256 + threadIdx.x;
  float4 v = ((const float4*)src)[i];
  ((short4*)dst)[i] = make_short4(f2b(v.x), f2b(v.y), f2b(v.z), f2b(v.w));
}

// ---------------------------------------------------------------------------
// RMSNorm: one block (256 thr) per row of 1024 f32 -> bf16
// ---------------------------------------------------------------------------
__global__ void k_rms(const float* __restrict__ x, const float* __restrict__ w,
                      short* __restrict__ out) {
  int row = blockIdx.x;
  int tid = threadIdx.x;
  float4 v = *(const float4*)(x + (size_t)row * 1024 + tid * 4);
  float ss = v.x * v.x + v.y * v.y + v.z * v.z + v.w * v.w;
#pragma unroll
  for (int o = 1; o < 64; o <<= 1) ss += __shfl_xor(ss, o);
  __shared__ float sred[4];
  int wid = tid >> 6, lane = tid & 63;
  if (lane == 0) sred[wid] = ss;
  __syncthreads();
  float tot = sred[0] + sred[1] + sred[2] + sred[3];
  float r = rsqrtf(tot * (1.0f / 1024.0f) + 1e-6f);
  float4 wv = *(const float4*)(w + tid * 4);
  short4 o = make_short4(f2b(v.x * r * wv.x), f2b(v.y * r * wv.y),
                         f2b(v.z * r * wv.z), f2b(v.w * r * wv.w));
  *(short4*)(out + (size_t)row * 1024 + tid * 4) = o;
}

// ---------------------------------------------------------------------------
// Big GEMM: C = A[M,K] * W[N,K]^T, 256x256 tile, BK=64, 2-slot dbuf,
// 8 waves (2M x 4N, wave-tile 128x64), 4-phase schedule, counted vmcnt(8).
// MODE 1: outb = bf16(C)                 (gate)
// MODE 2: outb = bf16(silu(outb) * C)    (up)
// MODE 3: QKV epilogue
// ---------------------------------------------------------------------------
template<int MODE>
__global__ __launch_bounds__(512, 2) void k_gemm_big(
    const short* __restrict__ A, const short* __restrict__ Bw,
    int M, int N, int K, int gx,
    short* __restrict__ outb,
    short* __restrict__ q_b, short* __restrict__ k_b, short* __restrict__ vT_b,
    float* __restrict__ kc, float* __restrict__ vc) {
  __shared__ short As[2][256 * 64];  // 64 KB
  __shared__ short Bs[2][256 * 64];  // 64 KB
  int tid = threadIdx.x;
  int nwg = gridDim.x, bid = blockIdx.x;
  int swz = (bid & 7) * (nwg >> 3) + (bid >> 3);
  int bx = swz % gx, by = swz / gx;
  int m0 = by * 256, n0 = bx * 256;
  int w = tid >> 6, l = tid & 63;
  int wr = w >> 2, wc = w & 3;
  int lr = l & 15, lseg = l >> 4;
  f32x4 acc[2][2][4][2] = {};
  int nk = K >> 6;
  const short* Ab = A + (size_t)m0 * K;
  const short* Bb = Bw + (size_t)n0 * K;

  // prologue: A(0), B(0), A(1) fully staged (12 loads/thread)
#pragma unroll
  for (int r = 0; r < 4; ++r) stage_round512(Ab, K, &As[0][0], tid, r * 64);
#pragma unroll
  for (int r = 0; r < 4; ++r) stage_round512(Bb, K, &Bs[0][0], tid, r * 64);
#pragma unroll
  for (int r = 0; r < 4; ++r) stage_round512(Ab + 64, K, &As[1][0], tid, r * 64);
  VMCNT(0);
  BARF();

  bf16x8 ar[4][2], br[2][2];
#pragma unroll 1
  for (int u = 0; u < nk; ++u) {
    int s = u & 1;
    short* Asl = &As[s][0];
    short* Bsl = &Bs[s][0];
    const short* Ag2 = Ab + (u + 2) * 64;
    const short* Bg1 = Bb + (u + 1) * 64;

    // ---- phase 0: (ah0, bh0); stage B(u+1) -> Bs[s^1]
    if (u + 1 < nk) {
#pragma unroll
      for (int r = 0; r < 4; ++r) stage_round512(Bg1, K, &Bs[s ^ 1][0], tid, r * 64);
    }
    VMCNT(8);
    BARF();
#pragma unroll
    for (int i = 0; i < 4; ++i)
#pragma unroll
      for (int kk = 0; kk < 2; ++kk)
        ar[i][kk] = frag64(Asl, wr * 128 + i * 16 + lr, kk * 4 + lseg);
#pragma unroll
    for (int j = 0; j < 2; ++j)
#pragma unroll
      for (int kk = 0; kk < 2; ++kk)
        br[j][kk] = frag64(Bsl, wc * 64 + j * 16 + lr, kk * 4 + lseg);
    LGKM0();
    __builtin_amdgcn_s_setprio(1);
#pragma unroll
    for (int i = 0; i < 4; ++i)
#pragma unroll
      for (int j = 0; j < 2; ++j) {
        acc[0][0][i][j] = mma16(ar[i][0], br[j][0], acc[0][0][i][j]);
        acc[0][0][i][j] = mma16(ar[i][1], br[j][1], acc[0][0][i][j]);
      }
    __builtin_amdgcn_s_setprio(0);
    BARF();

    // ---- phase 1: (ah0, bh1); stage A(u+2) rounds 0,2 (freed by p0)
    if (u + 2 < nk) {
      stage_round512(Ag2, K, Asl, tid, 0);
      stage_round512(Ag2, K, Asl, tid, 128);
    }
#pragma unroll
    for (int j = 0; j < 2; ++j)
#pragma unroll
      for (int kk = 0; kk < 2; ++kk)
        br[j][kk] = frag64(Bsl, wc * 64 + 32 + j * 16 + lr, kk * 4 + lseg);
    LGKM0();
    __builtin_amdgcn_s_setprio(1);
#pragma unroll
    for (int i = 0; i < 4; ++i)
#pragma unroll
      for (int j = 0; j < 2; ++j) {
        acc[0][1][i][j] = mma16(ar[i][0], br[j][0], acc[0][1][i][j]);
        acc[0][1][i][j] = mma16(ar[i][1], br[j][1], acc[0][1][i][j]);
      }
    __builtin_amdgcn_s_setprio(0);

    // ---- phase 2: (ah1, bh0)
#pragma unroll
    for (int i = 0; i < 4; ++i)
#pragma unroll
      for (int kk = 0; kk < 2; ++kk)
        ar[i][kk] = frag64(Asl, wr * 128 + 64 + i * 16 + lr, kk * 4 + lseg);
#pragma unroll
    for (int j = 0; j < 2; ++j)
#pragma unroll
      for (int kk = 0; kk < 2; ++kk)
        br[j][kk] = frag64(Bsl, wc * 64 + j * 16 + lr, kk * 4 + lseg);
    LGKM0();
    __builtin_amdgcn_s_setprio(1);
#pragma unroll
    for (int i = 0; i < 4; ++i)
#pragma unroll
      for (int j = 0; j < 2; ++j) {
        acc[1][0][i][j] = mma16(ar[i][0], br[j][0], acc[1][0][i][j]);
        acc[1][0][i][j] = mma16(ar[i][1], br[j][1], acc[1][0][i][j]);
      }
    __builtin_amdgcn_s_setprio(0);
    BARF();

    // ---- phase 3: (ah1, bh1); stage A(u+2) rounds 1,3 (freed by p2)
    if (u + 2 < nk) {
      stage_round512(Ag2, K, Asl, tid, 64);
      stage_round512(Ag2, K, Asl, tid, 192);
    }
#pragma unroll
    for (int j = 0; j < 2; ++j)
#pragma unroll
      for (int kk = 0; kk < 2; ++kk)
        br[j][kk] = frag64(Bsl, wc * 64 + 32 + j * 16 + lr, kk * 4 + lseg);
    LGKM0();
    __builtin_amdgcn_s_setprio(1);
#pragma unroll
    for (int i = 0; i < 4; ++i)
#pragma unroll
      for (int j = 0; j < 2; ++j) {
        acc[1][1][i][j] = mma16(ar[i][0], br[j][0], acc[1][1][i][j]);
        acc[1][1][i][j] = mma16(ar[i][1], br[j][1], acc[1][1][i][j]);
      }
    __builtin_amdgcn_s_setprio(0);
    BARF();
  }

  // epilogue: C frag col = l&15, row = (l>>4)*4 + r
#pragma unroll
  for (int ah = 0; ah < 2; ++ah) {
#pragma unroll
    for (int bh = 0; bh < 2; ++bh) {
#pragma unroll
      for (int i = 0; i < 4; ++i) {
#pragma unroll
        for (int j = 0; j < 2; ++j) {
#pragma unroll
          for (int r = 0; r < 4; ++r) {
            int m = m0 + wr * 128 + ah * 64 + i * 16 + (l >> 4) * 4 + r;
            int n = n0 + wc * 64 + bh * 32 + j * 16 + lr;
            float f = acc[ah][bh][i][j][r];
            if (MODE == 1) {
              outb[(size_t)m * N + n] = f2b(f);
            } else if (MODE == 2) {
              float g = b2f(outb[(size_t)m * N + n]);
              float sg = g / (1.0f + __expf(-g));
              outb[(size_t)m * N + n] = f2b(sg * f);
            } else {
              int jj = n >> 10, hh = (n >> 6) & 15, dh = n & 63;
              int b_ = m >> 11, t = m & 2047;
              int bhh = b_ * 16 + hh;
              size_t idx = ((size_t)bhh * 2048 + t) * 64 + dh;
              if (jj == 0) {
                q_b[idx] = f2b(f);
              } else if (jj == 1) {
                k_b[idx] = f2b(f);
                kc[idx] = f;
              } else {
                vT_b[((size_t)bhh * 64 + dh) * 2048 + t] = f2b(f);
                vc[idx] = f;
              }
            }
          }
        }
      }
    }
  }
}

// ---------------------------------------------------------------------------
// Skinny GEMM: 128x64 tile, BK=64, ring-3, 4 waves (2M x 2N, wave 64x32).
// outf[m,n] = C + res[m,n]   (proj, down; N=1024 -> grid 32x16=512, 2 blk/CU)
// ---------------------------------------------------------------------------
__global__ __launch_bounds__(256, 2) void k_gemm_skinny(
    const short* __restrict__ A, const short* __restrict__ Bw,
    int M, int N, int K, int gx,
    const float* __restrict__ res, float* __restrict__ outf) {
  __shared__ short As[3][128 * 64];  // 48 KB
  __shared__ short Bs[3][64 * 64];   // 24 KB
  int tid = threadIdx.x;
  int nwg = gridDim.x, bid = blockIdx.x;
  int swz = (bid & 7) * (nwg >> 3) + (bid >> 3);
  int bx = swz % gx, by = swz / gx;
  int m0 = by * 128, n0 = bx * 64;
  int w = tid >> 6, l = tid & 63;
  int wr = w >> 1, wc = w & 1;
  int lr = l & 15, lseg = l >> 4;
  f32x4 acc[4][2] = {};
  int nk = K >> 6;
  const short* Ab = A + (size_t)m0 * K;
  const short* Bb = Bw + (size_t)n0 * K;

  stage_swz<128>(Ab, K, &As[0][0], tid);
  stage_swz<64>(Bb, K, &Bs[0][0], tid);
  stage_swz<128>(Ab + 64, K, &As[1][0], tid);
  stage_swz<64>(Bb + 64, K, &Bs[1][0], tid);

#pragma unroll 1
  for (int u = 0; u < nk; ++u) {
    VMCNT(6);   // tiles u+1, u+2 may stay in flight (6 loads/tile)
    BARF();
    if (u + 2 < nk) {
      int sl = (u + 2) % 3;
      stage_swz<128>(Ab + (u + 2) * 64, K, &As[sl][0], tid);
      stage_swz<64>(Bb + (u + 2) * 64, K, &Bs[sl][0], tid);
    }
    const short* Asl = &As[u % 3][0];
    const short* Bsl = &Bs[u % 3][0];
    bf16x8 ar[4][2], br[2][2];
#pragma unroll
    for (int i = 0; i < 4; ++i)
#pragma unroll
      for (int kk = 0; kk < 2; ++kk)
        ar[i][kk] = frag64(Asl, wr * 64 + i * 16 + lr, kk * 4 + lseg);
#pragma unroll
    for (int j = 0; j < 2; ++j)
#pragma unroll
      for (int kk = 0; kk < 2; ++kk)
        br[j][kk] = frag64(Bsl, wc * 32 + j * 16 + lr, kk * 4 + lseg);
    LGKM0();
    __builtin_amdgcn_s_setprio(1);
#pragma unroll
    for (int i = 0; i < 4; ++i)
#pragma unroll
      for (int j = 0; j < 2; ++j) {
        acc[i][j] = mma16(ar[i][0], br[j][0], acc[i][j]);
        acc[i][j] = mma16(ar[i][1], br[j][1], acc[i][j]);
      }
    __builtin_amdgcn_s_setprio(0);
  }

#pragma unroll
  for (int i = 0; i < 4; ++i) {
#pragma unroll
    for (int j = 0; j < 2; ++j) {
#pragma unroll
      for (int r = 0; r < 4; ++r) {
        int m = m0 + wr * 64 + i * 16 + (l >> 4) * 4 + r;
        int n = n0 + wc * 32 + j * 16 + lr;
        outf[(size_t)m * N + n] = acc[i][j][r] + res[(size_t)m * N + n];
      }
    }
  }
}

// ---------------------------------------------------------------------------
// Causal flash attention (unchanged; 0-conflict swizzled LDS).
// ---------------------------------------------------------------------------
__global__ __launch_bounds__(256) void k_attn(const short* __restrict__ q_b,
                                              const short* __restrict__ k_b,
                                              const short* __restrict__ vT_b,
                                              short* __restrict__ o_b) {
  __shared__ short Qs[64 * 64];
  __shared__ short Ks[64 * 64];
  __shared__ short VTs[64 * 64];
  __shared__ short Ps[4][16 * 88];
  int tid = threadIdx.x;
  int w = tid >> 6, l = tid & 63;
  int qt = blockIdx.x, bh = blockIdx.y;
  int q0 = qt * 64;

  stage_swz<64>(q_b + ((size_t)bh * 2048 + q0) * 64, 64, Qs, tid);

  f32x4 acc[4] = {};
  float mrow = -INFINITY, dden = 0.0f;
  int qg = q0 + w * 16 + (l & 15);
  int nt = qt + 1;

  for (int kt = 0; kt < nt; ++kt) {
    int kv0 = kt * 64;
    __syncthreads();
    stage_swz<64>(k_b + ((size_t)bh * 2048 + kv0) * 64, 64, Ks, tid);
    stage_swz<64>(vT_b + (size_t)bh * 64 * 2048 + kv0, 2048, VTs, tid);
    __syncthreads();

    bf16x8 qf[2];
#pragma unroll
    for (int kk = 0; kk < 2; ++kk) {
      int rowq = w * 16 + (l & 15);
      int s = kk * 4 + (l >> 4);
      qf[kk] = *(const bf16x8*)(Qs + rowq * 64 + ((s ^ (rowq & 7)) << 3));
    }
    f32x4 st[4];
#pragma unroll
    for (int i = 0; i < 4; ++i) {
      f32x4 z = {};
#pragma unroll
      for (int kk = 0; kk < 2; ++kk) {
        int rowk = i * 16 + (l & 15);
        int s = kk * 4 + (l >> 4);
        bf16x8 kf = *(const bf16x8*)(Ks + rowk * 64 + ((s ^ (rowk & 7)) << 3));
        z = mma16(kf, qf[kk], z);
      }
      st[i] = z;
    }

    float p[16];
    float pm = -INFINITY;
    bool last = (kt == qt);
#pragma unroll
    for (int i = 0; i < 4; ++i)
#pragma unroll
      for (int r = 0; r < 4; ++r) {
        int key = kv0 + i * 16 + (l >> 4) * 4 + r;
        float v = st[i][r] * 0.125f;
        if (last && key > qg) v = -INFINITY;
        p[i * 4 + r] = v;
        pm = fmaxf(pm, v);
      }
    pm = fmaxf(pm, __shfl_xor(pm, 16));
    pm = fmaxf(pm, __shfl_xor(pm, 32));
    float nm = fmaxf(mrow, pm);
    float corr = __expf(mrow - nm);
    float ds_ = 0.0f;
#pragma unroll
    for (int kx = 0; kx < 16; ++kx) {
      float pv = __expf(p[kx] - nm);
      p[kx] = pv;
      ds_ += pv;
    }
    ds_ += __shfl_xor(ds_, 16);
    ds_ += __shfl_xor(ds_, 32);
    dden = dden * corr + ds_;
    mrow = nm;
#pragma unroll
    for (int r = 0; r < 4; ++r) {
      float cr = __shfl(corr, (l >> 4) * 4 + r);
#pragma unroll
      for (int jf = 0; jf < 4; ++jf) acc[jf][r] *= cr;
    }

    short* pw = &Ps[w][0];
#pragma unroll
    for (int i = 0; i < 4; ++i) {
      uint32_t lo = (uint32_t)(uint16_t)f2b(p[i * 4 + 0]) |
                    ((uint32_t)(uint16_t)f2b(p[i * 4 + 1]) << 16);
      uint32_t hi = (uint32_t)(uint16_t)f2b(p[i * 4 + 2]) |
                    ((uint32_t)(uint16_t)f2b(p[i * 4 + 3]) << 16);
      uint2 pk;
      pk.x = lo;
      pk.y = hi;
      *(uint2*)(pw + (l & 15) * 88 + i * 16 + ((l >> 4) << 2)) = pk;
    }

#pragma unroll
    for (int kk = 0; kk < 2; ++kk) {
      bf16x8 pa = *(const bf16x8*)(pw + (l & 15) * 88 + kk * 32 + ((l >> 4) << 3));
#pragma unroll
      for (int jf = 0; jf < 4; ++jf) {
        int rowv = jf * 16 + (l & 15);
        int s = kk * 4 + (l >> 4);
        bf16x8 vb = *(const bf16x8*)(VTs + rowv * 64 + ((s ^ (rowv & 7)) << 3));
        acc[jf] = mma16(pa, vb, acc[jf]);
      }
    }
  }

  int hh = bh & 15, b_ = bh >> 4;
#pragma unroll
  for (int r = 0; r < 4; ++r) {
    float dq = __shfl(dden, (l >> 4) * 4 + r);
    float inv = 1.0f / dq;
    int mg = q0 + w * 16 + (l >> 4) * 4 + r;
    size_t rowoff = ((size_t)b_ * 2048 + mg) * 1024 + hh * 64;
#pragma unroll
    for (int jf = 0; jf < 4; ++jf)
      o_b[rowoff + jf * 16 + (l & 15)] = f2b(acc[jf][r] * inv);
  }
}

// ---------------------------------------------------------------------------
// Launch
// ---------------------------------------------------------------------------
extern "C" void kernel_launch(void* const* d_in, const int* in_sizes, int n_in,
                              void* d_out, int out_size, void* d_ws, size_t ws_size,
                              hipStream_t stream) {
  const float* x     = (const float*)d_in[0];
  const float* wn1   = (const float*)d_in[1];
  const float* wqkv  = (const float*)d_in[2];
  const float* wproj = (const float*)d_in[3];
  const float* wn2   = (const float*)d_in[4];
  const float* wgate = (const float*)d_in[5];
  const float* wup   = (const float*)d_in[6];
  const float* wdown = (const float*)d_in[7];
  float* out = (float*)d_out;
  char* ws = (char*)d_ws;

  short* wqkv_b  = (short*)(ws + 0);         //  6 MB
  short* wproj_b = (short*)(ws + 6291456);   //  2 MB
  short* wgate_b = (short*)(ws + 8388608);   //  8 MB
  short* wup_b   = (short*)(ws + 16777216);  //  8 MB
  short* wdown_b = (short*)(ws + 25165824);  //  8 MB
  short* h_b     = (short*)(ws + 33554432);  //  8 MB (h, then h2)
  short* q_b     = (short*)(ws + 41943040);  //  8 MB
  short* k_b     = (short*)(ws + 50331648);  //  8 MB
  short* vT_b    = (short*)(ws + 58720256);  //  8 MB
  short* ao_b    = (short*)(ws + 67108864);  //  8 MB
  short* act_b   = q_b;   // 32 MB alias over q/k/vT/ao (free after attention)
  float* x1 = out;
  float* kc = out + 4194304;
  float* vc = out + 8388608;

  k_cvt_all<<<16384, 256, 0, stream>>>(wqkv, wqkv_b, wproj, wproj_b,
                                       wgate, wgate_b, wup, wup_b, wdown, wdown_b);

  k_rms<<<4096, 256, 0, stream>>>(x, wn1, h_b);

  // qkv = h @ w_qkv^T  (grid 16x12 = 192 blocks)
  k_gemm_big<3><<<192, 512, 0, stream>>>(h_b, wqkv_b, 4096, 3072, 1024, 12,
                                         nullptr, q_b, k_b, vT_b, kc, vc);

  k_attn<<<dim3(32, 32), 256, 0, stream>>>(q_b, k_b, vT_b, ao_b);

  // x1 = x + attn @ w_proj^T  (grid 32x16 = 512 blocks)
  k_gemm_skinny<<<512, 256, 0, stream>>>(ao_b, wproj_b, 4096, 1024, 1024, 16,
                                         x, x1);

  k_rms<<<4096, 256, 0, stream>>>(x1, wn2, h_b);

  // gate = h2 @ w_gate^T (bf16)
  k_gemm_big<1><<<256, 512, 0, stream>>>(h_b, wgate_b, 4096, 4096, 1024, 16,
                                         act_b, nullptr, nullptr, nullptr, nullptr, nullptr);
  // act = silu(gate) * (h2 @ w_up^T)
  k_gemm_big<2><<<256, 512, 0, stream>>>(h_b, wup_b, 4096, 4096, 1024, 16,
                                         act_b, nullptr, nullptr, nullptr, nullptr, nullptr);
  // x_out = x1 + act @ w_down^T
  k_gemm_skinny<<<512, 256, 0, stream>>>(act_b, wdown_b, 4096, 1024, 4096, 16,
                                         x1, out);
}